// Round 9
// baseline (4207.861 us; speedup 1.0000x reference)
//
#include <hip/hip_runtime.h>
#include <hip/hip_bf16.h>

#define NUSERS  50000
#define NNODES  100000
#define NEDGES  3200000
#define DIM     64
#define OSTRIDE 256   // output row stride: (3+1)*64
#define NBUCK   391   // ceil(NNODES/256): one 256-row bucket per workgroup
#define EPB     8192  // edges per block in bucketing kernels
#define NPBLK   391   // ceil(NEDGES/EPB)
#define NCOLB   1792  // col>>6 sort bins (1563 used), 256*7
#define LSTR    68    // LDS side row stride in f32 (pad: banks spread 4/row)

typedef unsigned short u16;
typedef unsigned int u32;
typedef __attribute__((ext_vector_type(8))) short bf16x8;
typedef __attribute__((ext_vector_type(4))) float f32x4;

__device__ __forceinline__ float us2f(u16 u) {
    return __uint_as_float((u32)u << 16);
}
__device__ __forceinline__ u16 f2b(float f) {           // f32 -> bf16 RNE bits
    u32 u = __float_as_uint(f);
    return (u16)((u + 0x7fffu + ((u >> 16) & 1u)) >> 16);
}

// ---------------------------------------------------------------------------
// out[:, 0:64] = concat(ue, ie) (fp32); ego[N][64] bf16
// ---------------------------------------------------------------------------
__global__ __launch_bounds__(256) void init_ego(const float* __restrict__ ue,
                                                const float* __restrict__ ie,
                                                float* __restrict__ out,
                                                u32*   __restrict__ ego32) {
    int gid = blockIdx.x * 256 + threadIdx.x;
    if (gid >= NNODES * 16) return;
    int node = gid >> 4, c = gid & 15;
    float4 v = (node < NUSERS)
        ? ((const float4*)ue)[node * 16 + c]
        : ((const float4*)ie)[(size_t)(node - NUSERS) * 16 + c];
    ((float4*)(out + (size_t)node * OSTRIDE))[c] = v;
    u32* d = ego32 + (size_t)node * 32 + 2 * c;
    d[0] = (u32)f2b(v.x) | ((u32)f2b(v.y) << 16);
    d[1] = (u32)f2b(v.z) | ((u32)f2b(v.w) << 16);
}

// ---------------------------------------------------------------------------
// Bucketed counting sort by row>>8 (R4, proven): count -> scan -> place
// ---------------------------------------------------------------------------
__global__ __launch_bounds__(256) void bucket_count(const int* __restrict__ rows,
                                                    int* __restrict__ bcount) {
    __shared__ int lh[NBUCK];
    int tid = threadIdx.x;
    for (int i = tid; i < NBUCK; i += 256) lh[i] = 0;
    __syncthreads();
    int e0 = blockIdx.x * EPB, e1 = min(e0 + EPB, NEDGES);
    for (int e = e0 + tid; e < e1; e += 256)
        atomicAdd(&lh[rows[e] >> 8], 1);
    __syncthreads();
    for (int i = tid; i < NBUCK; i += 256)
        if (lh[i]) atomicAdd(&bcount[i], lh[i]);
}

__global__ __launch_bounds__(512) void bucket_scan(const int* __restrict__ bcount,
                                                   int* __restrict__ bbase,
                                                   int* __restrict__ bcursor) {
    __shared__ int sc[512];
    int tid = threadIdx.x;
    int v = (tid < NBUCK) ? bcount[tid] : 0;
    sc[tid] = v;
    __syncthreads();
    for (int off = 1; off < 512; off <<= 1) {
        int t = (tid >= off) ? sc[tid - off] : 0;
        __syncthreads();
        sc[tid] += t;
        __syncthreads();
    }
    if (tid < NBUCK) {
        int excl = sc[tid] - v;
        bbase[tid] = excl;
        bcursor[tid] = excl;
    }
    if (tid == 0) bbase[NBUCK] = NEDGES;
}

__global__ __launch_bounds__(256) void bucket_place(const int*   __restrict__ rows,
                                                    const int*   __restrict__ cols,
                                                    const float* __restrict__ vals,
                                                    int*  __restrict__ bcursor,
                                                    int2* __restrict__ tmp) {
    __shared__ int lh[NBUCK];
    int tid = threadIdx.x;
    for (int i = tid; i < NBUCK; i += 256) lh[i] = 0;
    __syncthreads();
    int e0 = blockIdx.x * EPB, e1 = min(e0 + EPB, NEDGES);
    for (int e = e0 + tid; e < e1; e += 256)
        atomicAdd(&lh[rows[e] >> 8], 1);
    __syncthreads();
    for (int i = tid; i < NBUCK; i += 256) {
        int c = lh[i];
        lh[i] = c ? atomicAdd(&bcursor[i], c) : 0;
    }
    __syncthreads();
    for (int e = e0 + tid; e < e1; e += 256) {
        int r = rows[e];
        int p = atomicAdd(&lh[r >> 8], 1);
        tmp[p] = make_int2(((r & 255) << 20) | cols[e], (int)f2b(vals[e]));
    }
}

// ---------------------------------------------------------------------------
// Second pass: within each row-bucket, sort edges by col>>6 so every WG
// sweeps the ego table in ascending column order (L2 streaming).
// ---------------------------------------------------------------------------
__global__ __launch_bounds__(256) void bucket_to_colsort(const int*  __restrict__ bbase,
                                                         const int2* __restrict__ tmp,
                                                         u32* __restrict__ colLR,
                                                         u16* __restrict__ valS) {
    __shared__ int cnt[NCOLB];
    __shared__ int tsum[256];
    int b = blockIdx.x, tid = threadIdx.x;
    int j0 = bbase[b], j1 = bbase[b + 1];
    for (int i = tid; i < NCOLB; i += 256) cnt[i] = 0;
    __syncthreads();
    for (int j = j0 + tid; j < j1; j += 256)
        atomicAdd(&cnt[(tmp[j].x & 0xFFFFF) >> 6], 1);
    __syncthreads();
    int base_i = tid * 7, tot = 0;
    #pragma unroll
    for (int i = 0; i < 7; ++i) tot += cnt[base_i + i];
    tsum[tid] = tot;
    __syncthreads();
    for (int off = 1; off < 256; off <<= 1) {
        int t = (tid >= off) ? tsum[tid - off] : 0;
        __syncthreads();
        tsum[tid] += t;
        __syncthreads();
    }
    int run = j0 + tsum[tid] - tot;
    #pragma unroll
    for (int i = 0; i < 7; ++i) {
        int c = cnt[base_i + i];
        cnt[base_i + i] = run;
        run += c;
    }
    __syncthreads();
    for (int j = j0 + tid; j < j1; j += 256) {
        int2 t2 = tmp[j];
        int q = atomicAdd(&cnt[(t2.x & 0xFFFFF) >> 6], 1);
        colLR[q] = (u32)t2.x;
        valS[q]  = (u16)t2.y;
    }
}

// ---------------------------------------------------------------------------
// Weights -> fragment-ordered bf16, with k permuted to the LDS dim order:
// permuted dim pd<32 -> real dim 2*pd (low bf16), pd>=32 -> 2*(pd-32)+1 (high).
// k<64: side @ Wg row real(pd);  k>=64: (ego*side) @ Wb row real(pd).
// ---------------------------------------------------------------------------
__global__ __launch_bounds__(256) void weights_prep(const float* __restrict__ Wg,
                                                    const float* __restrict__ Wb,
                                                    u16* __restrict__ wpre) {
    int layer = blockIdx.y;
    int idx = blockIdx.x * 256 + threadIdx.x;   // 0..8191
    int e = idx & 7, l = (idx >> 3) & 63, t = (idx >> 9) & 3, s = idx >> 11;
    int k = 32 * s + 8 * (l >> 4) + e;          // logical k, 0..127
    int pd = k & 63;
    int rdim = (pd < 32) ? 2 * pd : 2 * (pd - 32) + 1;
    int n = 16 * t + (l & 15);
    float wv = (k < 64) ? Wg[layer * 4096 + rdim * 64 + n]
                        : Wb[layer * 4096 + rdim * 64 + n];
    wpre[layer * 8192 + idx] = f2b(wv);
}

// ---------------------------------------------------------------------------
// Fused layer, one WG per 256-row bucket (391 WGs, all co-resident, 2/CU):
//  Phase A: col-sorted edge sweep; side accumulated in LDS via ds_add_f32.
//           lane=(h,d): h=edge parity, d=dword(2 dims). Bank-conflict-free.
//  Phase B: MFMA dense [side | ego*side] @ [Wg;Wb] from LDS, + bias,
//           leaky-relu, inline L2-normalize -> out; raw bf16 -> egoOut.
// ---------------------------------------------------------------------------
__global__ __launch_bounds__(256) void fused_layer(const int* __restrict__ bbase,
                                                   const u32* __restrict__ colLR,
                                                   const u16* __restrict__ valS,
                                                   const u16* __restrict__ egoIn,
                                                   u16*       __restrict__ egoOut,
                                                   float*     __restrict__ out,
                                                   const u16* __restrict__ wpre,
                                                   const float* __restrict__ bg,
                                                   const float* __restrict__ bb,
                                                   int layer) {
    __shared__ float side[256][LSTR];   // 69.6 KB; pd layout: [0..31]=even dims

    int tid = threadIdx.x;
    {   // zero LDS accumulators
        float2* sp = (float2*)&side[0][0];
        for (int i = tid; i < 256 * LSTR / 2; i += 256) sp[i] = make_float2(0.f, 0.f);
    }
    __syncthreads();

    int w = tid >> 6, lane = tid & 63;
    int h = lane >> 5, d = lane & 31;
    int b = blockIdx.x;
    int j0 = bbase[b], j1 = bbase[b + 1];

    // ---- Phase A: gather + LDS scatter-accumulate (col-sorted sweep) ----
    int e = j0 + w * 2 + h;             // this half-wave's edge slot, stride 8
    for (; e + 24 < j1; e += 32) {      // 4 edges in flight per slot
        u32 cl0 = colLR[e], cl1 = colLR[e + 8], cl2 = colLR[e + 16], cl3 = colLR[e + 24];
        float v0 = us2f(valS[e]),      v1 = us2f(valS[e + 8]),
              v2 = us2f(valS[e + 16]), v3 = us2f(valS[e + 24]);
        u32 g0 = *((const u32*)(egoIn + (size_t)(cl0 & 0xFFFFF) * DIM) + d);
        u32 g1 = *((const u32*)(egoIn + (size_t)(cl1 & 0xFFFFF) * DIM) + d);
        u32 g2 = *((const u32*)(egoIn + (size_t)(cl2 & 0xFFFFF) * DIM) + d);
        u32 g3 = *((const u32*)(egoIn + (size_t)(cl3 & 0xFFFFF) * DIM) + d);
        int r0 = cl0 >> 20, r1 = cl1 >> 20, r2 = cl2 >> 20, r3 = cl3 >> 20;
        atomicAdd(&side[r0][d],      v0 * __uint_as_float(g0 << 16));
        atomicAdd(&side[r0][32 + d], v0 * __uint_as_float(g0 & 0xFFFF0000u));
        atomicAdd(&side[r1][d],      v1 * __uint_as_float(g1 << 16));
        atomicAdd(&side[r1][32 + d], v1 * __uint_as_float(g1 & 0xFFFF0000u));
        atomicAdd(&side[r2][d],      v2 * __uint_as_float(g2 << 16));
        atomicAdd(&side[r2][32 + d], v2 * __uint_as_float(g2 & 0xFFFF0000u));
        atomicAdd(&side[r3][d],      v3 * __uint_as_float(g3 << 16));
        atomicAdd(&side[r3][32 + d], v3 * __uint_as_float(g3 & 0xFFFF0000u));
    }
    for (; e < j1; e += 8) {
        u32 cl = colLR[e];
        float v = us2f(valS[e]);
        u32 g = *((const u32*)(egoIn + (size_t)(cl & 0xFFFFF) * DIM) + d);
        int r = cl >> 20;
        atomicAdd(&side[r][d],      v * __uint_as_float(g << 16));
        atomicAdd(&side[r][32 + d], v * __uint_as_float(g & 0xFFFF0000u));
    }
    __syncthreads();

    // ---- Phase B: MFMA dense + bias + leaky-relu + inline normalize ----
    int g = lane >> 4, m = lane & 15;
    const bf16x8* W = (const bf16x8*)(wpre + layer * 8192);
    bf16x8 Bf[16];
    #pragma unroll
    for (int i = 0; i < 16; ++i) Bf[i] = W[i * 64 + lane];   // i = s*4+t
    float biasv[4];
    #pragma unroll
    for (int t = 0; t < 4; ++t)
        biasv[t] = bg[layer * 64 + 16 * t + m] + bb[layer * 64 + 16 * t + m];

    int rb = b * 256;
    for (int tile = w; tile < 16; tile += 4) {   // 4 row-tiles per wave
        int lr = tile * 16 + m;
        int row = rb + lr;
        int rowc = min(row, NNODES - 1);
        const float* srow = &side[lr][0];
        float s0[8], s1[8];
        #pragma unroll
        for (int i = 0; i < 8; ++i) { s0[i] = srow[8 * g + i]; s1[i] = srow[32 + 8 * g + i]; }
        const u32* erow = (const u32*)(egoIn + (size_t)rowc * DIM) + 8 * g;
        bf16x8 sf0, sf1, pf0, pf1;
        #pragma unroll
        for (int i = 0; i < 8; ++i) {
            u32 ew = erow[i];
            sf0[i] = (short)f2b(s0[i]);
            sf1[i] = (short)f2b(s1[i]);
            pf0[i] = (short)f2b(__uint_as_float(ew << 16) * s0[i]);
            pf1[i] = (short)f2b(__uint_as_float(ew & 0xFFFF0000u) * s1[i]);
        }
        f32x4 acc[4];
        #pragma unroll
        for (int t = 0; t < 4; ++t) {
            acc[t] = (f32x4){0.f, 0.f, 0.f, 0.f};
            acc[t] = __builtin_amdgcn_mfma_f32_16x16x32_bf16(sf0, Bf[t],      acc[t], 0, 0, 0);
            acc[t] = __builtin_amdgcn_mfma_f32_16x16x32_bf16(sf1, Bf[4 + t],  acc[t], 0, 0, 0);
            acc[t] = __builtin_amdgcn_mfma_f32_16x16x32_bf16(pf0, Bf[8 + t],  acc[t], 0, 0, 0);
            acc[t] = __builtin_amdgcn_mfma_f32_16x16x32_bf16(pf1, Bf[12 + t], acc[t], 0, 0, 0);
        }
        // epilogue: D col=16t+m, row=rb+tile*16+4g+r
        float vv[4][4], ss[4];
        #pragma unroll
        for (int r = 0; r < 4; ++r) {
            float sr = 0.f;
            #pragma unroll
            for (int t = 0; t < 4; ++t) {
                float v = acc[t][r] + biasv[t];
                v = v >= 0.f ? v : 0.2f * v;
                vv[t][r] = v;
                sr += v * v;
            }
            ss[r] = sr;
        }
        #pragma unroll
        for (int off = 1; off < 16; off <<= 1) {
            #pragma unroll
            for (int r = 0; r < 4; ++r) ss[r] += __shfl_xor(ss[r], off, 64);
        }
        #pragma unroll
        for (int r = 0; r < 4; ++r) {
            int row2 = rb + tile * 16 + 4 * g + r;
            if (row2 < NNODES) {
                float rn = 1.f / fmaxf(sqrtf(ss[r]), 1e-12f);
                #pragma unroll
                for (int t = 0; t < 4; ++t) {
                    out[(size_t)row2 * OSTRIDE + (layer + 1) * DIM + 16 * t + m] = vv[t][r] * rn;
                    egoOut[(size_t)row2 * DIM + 16 * t + m] = f2b(vv[t][r]);
                }
            }
        }
    }
}

// ---------------------------------------------------------------------------
extern "C" void kernel_launch(void* const* d_in, const int* in_sizes, int n_in,
                              void* d_out, int out_size, void* d_ws, size_t ws_size,
                              hipStream_t stream) {
    const float* ue   = (const float*)d_in[0];
    const float* ie   = (const float*)d_in[1];
    const float* Wg   = (const float*)d_in[2];
    const float* bg   = (const float*)d_in[3];
    const float* Wb   = (const float*)d_in[4];
    const float* bb   = (const float*)d_in[5];
    const int*   rows = (const int*)d_in[6];
    const int*   cols = (const int*)d_in[7];
    const float* vals = (const float*)d_in[8];
    float* out = (float*)d_out;

    // ws (~44.9 MB): colLR u32[E] | valS u16[E] | bucket meta | wpre[3*8192] |
    // tmp int2[E] (25.6MB) aliased after sort by egoA/egoB u16[N*64] ping-pong
    u32* colLR = (u32*)d_ws;
    u16* valS  = (u16*)(colLR + NEDGES);
    int* bcount  = (int*)(valS + NEDGES);
    int* bbase   = bcount + NBUCK;
    int* bcursor = bbase + NBUCK + 1;
    u16* wpre    = (u16*)(bcursor + NBUCK);
    uintptr_t tp = ((uintptr_t)(wpre + 3 * 8192) + 15) & ~(uintptr_t)15;
    int2* tmp = (int2*)tp;
    u16* egoA = (u16*)tp;                         // 12.8 MB
    u16* egoB = egoA + (size_t)NNODES * DIM;      // 12.8 MB

    hipMemsetAsync(bcount, 0, NBUCK * sizeof(int), stream);
    bucket_count<<<NPBLK, 256, 0, stream>>>(rows, bcount);
    bucket_scan<<<1, 512, 0, stream>>>(bcount, bbase, bcursor);
    bucket_place<<<NPBLK, 256, 0, stream>>>(rows, cols, vals, bcursor, tmp);
    bucket_to_colsort<<<NBUCK, 256, 0, stream>>>(bbase, tmp, colLR, valS);

    weights_prep<<<dim3(32, 3), 256, 0, stream>>>(Wg, Wb, wpre);

    // init_ego AFTER the col-sort: egoA aliases tmp
    init_ego<<<(NNODES * 16 + 255) / 256, 256, 0, stream>>>(ue, ie, out, (u32*)egoA);

    u16* ei = egoA; u16* eo = egoB;
    for (int l = 0; l < 3; ++l) {
        fused_layer<<<NBUCK, 256, 0, stream>>>(bbase, colLR, valS, ei, eo, out,
                                               wpre, bg, bb, l);
        u16* t = ei; ei = eo; eo = t;
    }
}

// Round 10
// 3660.955 us; speedup vs baseline: 1.1494x; 1.1494x over previous
//
#include <hip/hip_runtime.h>
#include <hip/hip_bf16.h>

#define NUSERS  50000
#define NNODES  100000
#define NEDGES  3200000
#define DIM     64
#define OSTRIDE 256   // output row stride: (3+1)*64
#define NBUCK   1563  // ceil(NNODES/64): one 64-row bucket per workgroup
#define EPB     8192  // edges per block in bucketing kernels
#define NPBLK   391   // ceil(NEDGES/EPB)
#define NCOLB   391   // col>>8 bins inside each bucket (sweep granularity 32KB)
#define LSTR    68    // LDS side row stride in f32

typedef unsigned short u16;
typedef unsigned int u32;
typedef __attribute__((ext_vector_type(8))) short bf16x8;
typedef __attribute__((ext_vector_type(4))) float f32x4;

__device__ __forceinline__ float us2f(u16 u) {
    return __uint_as_float((u32)u << 16);
}
__device__ __forceinline__ u16 f2b(float f) {           // f32 -> bf16 RNE bits
    u32 u = __float_as_uint(f);
    return (u16)((u + 0x7fffu + ((u >> 16) & 1u)) >> 16);
}

// ---------------------------------------------------------------------------
// out[:, 0:64] = concat(ue, ie) (fp32); ego[N][64] bf16
// ---------------------------------------------------------------------------
__global__ __launch_bounds__(256) void init_ego(const float* __restrict__ ue,
                                                const float* __restrict__ ie,
                                                float* __restrict__ out,
                                                u32*   __restrict__ ego32) {
    int gid = blockIdx.x * 256 + threadIdx.x;
    if (gid >= NNODES * 16) return;
    int node = gid >> 4, c = gid & 15;
    float4 v = (node < NUSERS)
        ? ((const float4*)ue)[node * 16 + c]
        : ((const float4*)ie)[(size_t)(node - NUSERS) * 16 + c];
    ((float4*)(out + (size_t)node * OSTRIDE))[c] = v;
    u32* d = ego32 + (size_t)node * 32 + 2 * c;
    d[0] = (u32)f2b(v.x) | ((u32)f2b(v.y) << 16);
    d[1] = (u32)f2b(v.z) | ((u32)f2b(v.w) << 16);
}

// ---------------------------------------------------------------------------
// Counting sort pass 1: by row>>6 (1563 buckets of 64 rows)
// ---------------------------------------------------------------------------
__global__ __launch_bounds__(256) void bucket_count(const int* __restrict__ rows,
                                                    int* __restrict__ bcount) {
    __shared__ int lh[NBUCK];
    int tid = threadIdx.x;
    for (int i = tid; i < NBUCK; i += 256) lh[i] = 0;
    __syncthreads();
    int e0 = blockIdx.x * EPB, e1 = min(e0 + EPB, NEDGES);
    for (int e = e0 + tid; e < e1; e += 256)
        atomicAdd(&lh[rows[e] >> 6], 1);
    __syncthreads();
    for (int i = tid; i < NBUCK; i += 256)
        if (lh[i]) atomicAdd(&bcount[i], lh[i]);
}

// single-block exclusive scan over NBUCK=1563 (512 threads, 4 chunks, carry)
__global__ __launch_bounds__(512) void bucket_scan(const int* __restrict__ bcount,
                                                   int* __restrict__ bbase,
                                                   int* __restrict__ bcursor) {
    __shared__ int sc[512];
    __shared__ int carry_s;
    int tid = threadIdx.x;
    if (tid == 0) carry_s = 0;
    __syncthreads();
    for (int base = 0; base < NBUCK; base += 512) {
        int i = base + tid;
        int v = (i < NBUCK) ? bcount[i] : 0;
        sc[tid] = v;
        __syncthreads();
        for (int off = 1; off < 512; off <<= 1) {
            int t = (tid >= off) ? sc[tid - off] : 0;
            __syncthreads();
            sc[tid] += t;
            __syncthreads();
        }
        int c = carry_s;
        if (i < NBUCK) {
            int excl = c + sc[tid] - v;
            bbase[i] = excl;
            bcursor[i] = excl;
        }
        int tot = sc[511];
        __syncthreads();
        if (tid == 0) carry_s = c + tot;
        __syncthreads();
    }
    if (tid == 0) bbase[NBUCK] = NEDGES;
}

__global__ __launch_bounds__(256) void bucket_place(const int*   __restrict__ rows,
                                                    const int*   __restrict__ cols,
                                                    const float* __restrict__ vals,
                                                    int*  __restrict__ bcursor,
                                                    int2* __restrict__ tmp) {
    __shared__ int lh[NBUCK];
    int tid = threadIdx.x;
    for (int i = tid; i < NBUCK; i += 256) lh[i] = 0;
    __syncthreads();
    int e0 = blockIdx.x * EPB, e1 = min(e0 + EPB, NEDGES);
    for (int e = e0 + tid; e < e1; e += 256)
        atomicAdd(&lh[rows[e] >> 6], 1);
    __syncthreads();
    for (int i = tid; i < NBUCK; i += 256) {
        int c = lh[i];
        lh[i] = c ? atomicAdd(&bcursor[i], c) : 0;
    }
    __syncthreads();
    for (int e = e0 + tid; e < e1; e += 256) {
        int r = rows[e];
        int p = atomicAdd(&lh[r >> 6], 1);
        tmp[p] = make_int2(((r & 63) << 20) | cols[e], (int)f2b(vals[e]));
    }
}

// ---------------------------------------------------------------------------
// Pass 2: within each 64-row bucket, order edges by col>>8 so all WGs sweep
// the ego table in ascending column order (co-scheduled column reuse).
// ---------------------------------------------------------------------------
__global__ __launch_bounds__(256) void bucket_colsort(const int*  __restrict__ bbase,
                                                      const int2* __restrict__ tmp,
                                                      u32* __restrict__ colLR,
                                                      u16* __restrict__ valS) {
    __shared__ int cnt[NCOLB + 1];
    __shared__ int tsum[256];
    int b = blockIdx.x, tid = threadIdx.x;
    int j0 = bbase[b], j1 = bbase[b + 1];
    for (int i = tid; i <= NCOLB; i += 256) cnt[i] = 0;
    __syncthreads();
    for (int j = j0 + tid; j < j1; j += 256)
        atomicAdd(&cnt[(tmp[j].x & 0xFFFFF) >> 8], 1);
    __syncthreads();
    int i0 = 2 * tid, i1 = 2 * tid + 1;          // 512 slots cover 391 bins
    int c0 = (i0 <= NCOLB) ? cnt[i0] : 0;
    int c1 = (i1 <= NCOLB) ? cnt[i1] : 0;
    int tot = c0 + c1;
    tsum[tid] = tot;
    __syncthreads();
    for (int off = 1; off < 256; off <<= 1) {
        int t = (tid >= off) ? tsum[tid - off] : 0;
        __syncthreads();
        tsum[tid] += t;
        __syncthreads();
    }
    int run = j0 + tsum[tid] - tot;
    if (i0 <= NCOLB) { cnt[i0] = run; run += c0; }
    if (i1 <= NCOLB) { cnt[i1] = run; }
    __syncthreads();
    for (int j = j0 + tid; j < j1; j += 256) {
        int2 t2 = tmp[j];
        int q = atomicAdd(&cnt[(t2.x & 0xFFFFF) >> 8], 1);
        colLR[q] = (u32)t2.x;
        valS[q]  = (u16)t2.y;
    }
}

// ---------------------------------------------------------------------------
// Weights -> fragment-ordered bf16, k permuted to LDS dim order:
// pd<32 -> real dim 2*pd (low bf16 of dword), pd>=32 -> 2*(pd-32)+1 (high).
// ---------------------------------------------------------------------------
__global__ __launch_bounds__(256) void weights_prep(const float* __restrict__ Wg,
                                                    const float* __restrict__ Wb,
                                                    u16* __restrict__ wpre) {
    int layer = blockIdx.y;
    int idx = blockIdx.x * 256 + threadIdx.x;   // 0..8191
    int e = idx & 7, l = (idx >> 3) & 63, t = (idx >> 9) & 3, s = idx >> 11;
    int k = 32 * s + 8 * (l >> 4) + e;          // logical k, 0..127
    int pd = k & 63;
    int rdim = (pd < 32) ? 2 * pd : 2 * (pd - 32) + 1;
    int n = 16 * t + (l & 15);
    float wv = (k < 64) ? Wg[layer * 4096 + rdim * 64 + n]
                        : Wb[layer * 4096 + rdim * 64 + n];
    wpre[layer * 8192 + idx] = f2b(wv);
}

// ---------------------------------------------------------------------------
// Fused layer: one WG per 64-row bucket (1563 WGs, 4/CU, 16 waves/CU).
//  Phase A: col-sorted gather sweep; side accumulated in LDS f32 atomics.
//           lane=(h,d); 8-deep unroll per half -> 16 edges in flight/wave.
//  Phase B: MFMA dense [side | ego*side] @ [Wg;Wb] + bias + leaky-relu +
//           inline L2-normalize -> out; raw bf16 -> egoOut. (R8-proven math)
// ---------------------------------------------------------------------------
__global__ __launch_bounds__(256, 4) void fused_layer(const int* __restrict__ bbase,
                                                      const u32* __restrict__ colLR,
                                                      const u16* __restrict__ valS,
                                                      const u16* __restrict__ egoIn,
                                                      u16*       __restrict__ egoOut,
                                                      float*     __restrict__ out,
                                                      const u16* __restrict__ wpre,
                                                      const float* __restrict__ bg,
                                                      const float* __restrict__ bb,
                                                      int layer) {
    __shared__ float side[64][LSTR];    // 17.4 KB

    int tid = threadIdx.x;
    {   // zero LDS accumulators
        float2* sp = (float2*)&side[0][0];
        for (int i = tid; i < 64 * LSTR / 2; i += 256) sp[i] = make_float2(0.f, 0.f);
    }
    __syncthreads();

    int w = tid >> 6, lane = tid & 63;
    int h = lane >> 5, d = lane & 31;
    int b = blockIdx.x;
    int j0 = bbase[b], j1 = bbase[b + 1];

    // ---- Phase A: col-sorted sweep, 8 half-slots, 8-deep unroll ----
    int e = j0 + w * 2 + h;             // slot id = w*2+h in 0..7, stride 8
    for (; e + 56 < j1; e += 64) {
        u32 cl[8]; float v[8]; u32 g[8];
        #pragma unroll
        for (int s = 0; s < 8; ++s) { cl[s] = colLR[e + 8 * s]; v[s] = us2f(valS[e + 8 * s]); }
        #pragma unroll
        for (int s = 0; s < 8; ++s)
            g[s] = *((const u32*)(egoIn + (size_t)(cl[s] & 0xFFFFF) * DIM) + d);
        #pragma unroll
        for (int s = 0; s < 8; ++s) {
            int r = cl[s] >> 20;
            atomicAdd(&side[r][d],      v[s] * __uint_as_float(g[s] << 16));
            atomicAdd(&side[r][32 + d], v[s] * __uint_as_float(g[s] & 0xFFFF0000u));
        }
    }
    for (; e < j1; e += 8) {
        u32 cl = colLR[e];
        float v = us2f(valS[e]);
        u32 g = *((const u32*)(egoIn + (size_t)(cl & 0xFFFFF) * DIM) + d);
        int r = cl >> 20;
        atomicAdd(&side[r][d],      v * __uint_as_float(g << 16));
        atomicAdd(&side[r][32 + d], v * __uint_as_float(g & 0xFFFF0000u));
    }
    __syncthreads();

    // ---- Phase B: MFMA dense + bias + leaky-relu + inline normalize ----
    int g2 = lane >> 4, m = lane & 15;
    const bf16x8* W = (const bf16x8*)(wpre + layer * 8192);
    bf16x8 Bf[16];
    #pragma unroll
    for (int i = 0; i < 16; ++i) Bf[i] = W[i * 64 + lane];   // i = s*4+t
    float biasv[4];
    #pragma unroll
    for (int t = 0; t < 4; ++t)
        biasv[t] = bg[layer * 64 + 16 * t + m] + bb[layer * 64 + 16 * t + m];

    int rb = b * 64;
    {
        int tile = w;                    // one 16-row tile per wave
        int lr = tile * 16 + m;
        int row = rb + lr;
        int rowc = min(row, NNODES - 1);
        const float* srow = &side[lr][0];
        float s0[8], s1[8];
        #pragma unroll
        for (int i = 0; i < 8; ++i) { s0[i] = srow[8 * g2 + i]; s1[i] = srow[32 + 8 * g2 + i]; }
        const u32* erow = (const u32*)(egoIn + (size_t)rowc * DIM) + 8 * g2;
        bf16x8 sf0, sf1, pf0, pf1;
        #pragma unroll
        for (int i = 0; i < 8; ++i) {
            u32 ew = erow[i];
            sf0[i] = (short)f2b(s0[i]);
            sf1[i] = (short)f2b(s1[i]);
            pf0[i] = (short)f2b(__uint_as_float(ew << 16) * s0[i]);
            pf1[i] = (short)f2b(__uint_as_float(ew & 0xFFFF0000u) * s1[i]);
        }
        f32x4 acc[4];
        #pragma unroll
        for (int t = 0; t < 4; ++t) {
            acc[t] = (f32x4){0.f, 0.f, 0.f, 0.f};
            acc[t] = __builtin_amdgcn_mfma_f32_16x16x32_bf16(sf0, Bf[t],      acc[t], 0, 0, 0);
            acc[t] = __builtin_amdgcn_mfma_f32_16x16x32_bf16(sf1, Bf[4 + t],  acc[t], 0, 0, 0);
            acc[t] = __builtin_amdgcn_mfma_f32_16x16x32_bf16(pf0, Bf[8 + t],  acc[t], 0, 0, 0);
            acc[t] = __builtin_amdgcn_mfma_f32_16x16x32_bf16(pf1, Bf[12 + t], acc[t], 0, 0, 0);
        }
        float vv[4][4], ss[4];
        #pragma unroll
        for (int r = 0; r < 4; ++r) {
            float sr = 0.f;
            #pragma unroll
            for (int t = 0; t < 4; ++t) {
                float v = acc[t][r] + biasv[t];
                v = v >= 0.f ? v : 0.2f * v;
                vv[t][r] = v;
                sr += v * v;
            }
            ss[r] = sr;
        }
        #pragma unroll
        for (int off = 1; off < 16; off <<= 1) {
            #pragma unroll
            for (int r = 0; r < 4; ++r) ss[r] += __shfl_xor(ss[r], off, 64);
        }
        #pragma unroll
        for (int r = 0; r < 4; ++r) {
            int row2 = rb + tile * 16 + 4 * g2 + r;
            if (row2 < NNODES) {
                float rn = 1.f / fmaxf(sqrtf(ss[r]), 1e-12f);
                #pragma unroll
                for (int t = 0; t < 4; ++t) {
                    out[(size_t)row2 * OSTRIDE + (layer + 1) * DIM + 16 * t + m] = vv[t][r] * rn;
                    egoOut[(size_t)row2 * DIM + 16 * t + m] = f2b(vv[t][r]);
                }
            }
        }
    }
}

// ---------------------------------------------------------------------------
extern "C" void kernel_launch(void* const* d_in, const int* in_sizes, int n_in,
                              void* d_out, int out_size, void* d_ws, size_t ws_size,
                              hipStream_t stream) {
    const float* ue   = (const float*)d_in[0];
    const float* ie   = (const float*)d_in[1];
    const float* Wg   = (const float*)d_in[2];
    const float* bg   = (const float*)d_in[3];
    const float* Wb   = (const float*)d_in[4];
    const float* bb   = (const float*)d_in[5];
    const int*   rows = (const int*)d_in[6];
    const int*   cols = (const int*)d_in[7];
    const float* vals = (const float*)d_in[8];
    float* out = (float*)d_out;

    // ws (~44.9 MB): colLR u32[E] | valS u16[E] | bucket meta | wpre[3*8192] |
    // tmp int2[E] (25.6MB) aliased after sort by egoA/egoB u16[N*64] ping-pong
    u32* colLR = (u32*)d_ws;
    u16* valS  = (u16*)(colLR + NEDGES);
    int* bcount  = (int*)(valS + NEDGES);
    int* bbase   = bcount + NBUCK;
    int* bcursor = bbase + NBUCK + 1;
    u16* wpre    = (u16*)(bcursor + NBUCK);
    uintptr_t tp = ((uintptr_t)(wpre + 3 * 8192) + 15) & ~(uintptr_t)15;
    int2* tmp = (int2*)tp;
    u16* egoA = (u16*)tp;                         // 12.8 MB
    u16* egoB = egoA + (size_t)NNODES * DIM;      // 12.8 MB

    hipMemsetAsync(bcount, 0, NBUCK * sizeof(int), stream);
    bucket_count<<<NPBLK, 256, 0, stream>>>(rows, bcount);
    bucket_scan<<<1, 512, 0, stream>>>(bcount, bbase, bcursor);
    bucket_place<<<NPBLK, 256, 0, stream>>>(rows, cols, vals, bcursor, tmp);
    bucket_colsort<<<NBUCK, 256, 0, stream>>>(bbase, tmp, colLR, valS);

    weights_prep<<<dim3(32, 3), 256, 0, stream>>>(Wg, Wb, wpre);

    // init_ego AFTER the col-sort: egoA aliases tmp
    init_ego<<<(NNODES * 16 + 255) / 256, 256, 0, stream>>>(ue, ie, out, (u32*)egoA);

    u16* ei = egoA; u16* eo = egoB;
    for (int l = 0; l < 3; ++l) {
        fused_layer<<<NBUCK, 256, 0, stream>>>(bbase, colLR, valS, ei, eo, out,
                                               wpre, bg, bb, l);
        u16* t = ei; ei = eo; eo = t;
    }
}

// Round 11
// 459.922 us; speedup vs baseline: 9.1491x; 7.9600x over previous
//
#include <hip/hip_runtime.h>
#include <hip/hip_bf16.h>

#define NUSERS  50000
#define NNODES  100000
#define NEDGES  3200000
#define DIM     64
#define OSTRIDE 256   // output row stride: (3+1)*64
#define NBUCK   391   // ceil(NNODES/256): 256-row buckets
#define EPB     8192  // edges per block in bucketing kernels
#define NPBLK   391   // ceil(NEDGES/EPB)
#define NCOLB   391   // col>>8 bins (100000>>8 = 390 max)

typedef unsigned short u16;
typedef unsigned int u32;
typedef __attribute__((ext_vector_type(8))) short bf16x8;
typedef __attribute__((ext_vector_type(4))) float f32x4;

__device__ __forceinline__ float us2f(u16 u) {
    return __uint_as_float((u32)u << 16);
}
__device__ __forceinline__ u16 f2b(float f) {           // f32 -> bf16 RNE bits
    u32 u = __float_as_uint(f);
    return (u16)((u + 0x7fffu + ((u >> 16) & 1u)) >> 16);
}

// ---------------------------------------------------------------------------
// out[:, 0:64] = concat(ue, ie) (fp32); ego[N][64] bf16
// ---------------------------------------------------------------------------
__global__ __launch_bounds__(256) void init_ego(const float* __restrict__ ue,
                                                const float* __restrict__ ie,
                                                float* __restrict__ out,
                                                u32*   __restrict__ ego32) {
    int gid = blockIdx.x * 256 + threadIdx.x;
    if (gid >= NNODES * 16) return;
    int node = gid >> 4, c = gid & 15;
    float4 v = (node < NUSERS)
        ? ((const float4*)ue)[node * 16 + c]
        : ((const float4*)ie)[(size_t)(node - NUSERS) * 16 + c];
    ((float4*)(out + (size_t)node * OSTRIDE))[c] = v;
    u32* d = ego32 + (size_t)node * 32 + 2 * c;
    d[0] = (u32)f2b(v.x) | ((u32)f2b(v.y) << 16);
    d[1] = (u32)f2b(v.z) | ((u32)f2b(v.w) << 16);
}

// ---------------------------------------------------------------------------
// Pass 1: counting sort by row>>8 into 256-row buckets (R4, proven)
// ---------------------------------------------------------------------------
__global__ __launch_bounds__(256) void bucket_count(const int* __restrict__ rows,
                                                    int* __restrict__ bcount) {
    __shared__ int lh[NBUCK];
    int tid = threadIdx.x;
    for (int i = tid; i < NBUCK; i += 256) lh[i] = 0;
    __syncthreads();
    int e0 = blockIdx.x * EPB, e1 = min(e0 + EPB, NEDGES);
    for (int e = e0 + tid; e < e1; e += 256)
        atomicAdd(&lh[rows[e] >> 8], 1);
    __syncthreads();
    for (int i = tid; i < NBUCK; i += 256)
        if (lh[i]) atomicAdd(&bcount[i], lh[i]);
}

__global__ __launch_bounds__(512) void bucket_scan(const int* __restrict__ bcount,
                                                   int* __restrict__ bbase,
                                                   int* __restrict__ bcursor) {
    __shared__ int sc[512];
    int tid = threadIdx.x;
    int v = (tid < NBUCK) ? bcount[tid] : 0;
    sc[tid] = v;
    __syncthreads();
    for (int off = 1; off < 512; off <<= 1) {
        int t = (tid >= off) ? sc[tid - off] : 0;
        __syncthreads();
        sc[tid] += t;
        __syncthreads();
    }
    if (tid < NBUCK) {
        int excl = sc[tid] - v;
        bbase[tid] = excl;
        bcursor[tid] = excl;
    }
    if (tid == 0) bbase[NBUCK] = NEDGES;
}

__global__ __launch_bounds__(256) void bucket_place(const int*   __restrict__ rows,
                                                    const int*   __restrict__ cols,
                                                    const float* __restrict__ vals,
                                                    int*  __restrict__ bcursor,
                                                    int2* __restrict__ tmp) {
    __shared__ int lh[NBUCK];
    int tid = threadIdx.x;
    for (int i = tid; i < NBUCK; i += 256) lh[i] = 0;
    __syncthreads();
    int e0 = blockIdx.x * EPB, e1 = min(e0 + EPB, NEDGES);
    for (int e = e0 + tid; e < e1; e += 256)
        atomicAdd(&lh[rows[e] >> 8], 1);
    __syncthreads();
    for (int i = tid; i < NBUCK; i += 256) {
        int c = lh[i];
        lh[i] = c ? atomicAdd(&bcursor[i], c) : 0;
    }
    __syncthreads();
    for (int e = e0 + tid; e < e1; e += 256) {
        int r = rows[e];
        int p = atomicAdd(&lh[r >> 8], 1);
        tmp[p] = make_int2(((r & 255) << 20) | cols[e], (int)f2b(vals[e]));
    }
}

// ---------------------------------------------------------------------------
// Pass 2 (NEW): within each 256-row bucket, order edges by col>>8 bin.
// Writes the bin-ordered stream to colT/valT (contiguous 48KB window/bucket).
// ---------------------------------------------------------------------------
__global__ __launch_bounds__(256) void bucket_colsort(const int*  __restrict__ bbase,
                                                      const int2* __restrict__ tmp,
                                                      u32* __restrict__ colT,
                                                      u16* __restrict__ valT) {
    __shared__ int cnt[NCOLB];
    __shared__ int tsum[256];
    int b = blockIdx.x, tid = threadIdx.x;
    int j0 = bbase[b], j1 = bbase[b + 1];
    for (int i = tid; i < NCOLB; i += 256) cnt[i] = 0;
    __syncthreads();
    for (int j = j0 + tid; j < j1; j += 256)
        atomicAdd(&cnt[(tmp[j].x & 0xFFFFF) >> 8], 1);
    __syncthreads();
    int i0 = 2 * tid, i1 = 2 * tid + 1;
    int c0 = (i0 < NCOLB) ? cnt[i0] : 0;
    int c1 = (i1 < NCOLB) ? cnt[i1] : 0;
    int tot = c0 + c1;
    tsum[tid] = tot;
    __syncthreads();
    for (int off = 1; off < 256; off <<= 1) {
        int t = (tid >= off) ? tsum[tid - off] : 0;
        __syncthreads();
        tsum[tid] += t;
        __syncthreads();
    }
    int run = j0 + tsum[tid] - tot;
    if (i0 < NCOLB) { cnt[i0] = run; run += c0; }
    if (i1 < NCOLB) cnt[i1] = run;
    __syncthreads();
    for (int j = j0 + tid; j < j1; j += 256) {
        int2 t2 = tmp[j];
        int q = atomicAdd(&cnt[(t2.x & 0xFFFFF) >> 8], 1);
        colT[q] = (u32)t2.x;
        valT[q] = (u16)t2.y;
    }
}

// ---------------------------------------------------------------------------
// Pass 3: bin-ordered stream -> row-major CSR. Per-row edges land ~col-sorted
// (approximate stability is fine: sweep granularity is 256-col bins).
// ---------------------------------------------------------------------------
__global__ __launch_bounds__(256) void bucket_to_csr(const int* __restrict__ bbase,
                                                     const u32* __restrict__ colT,
                                                     const u16* __restrict__ valT,
                                                     int* __restrict__ rs,
                                                     int* __restrict__ colS,
                                                     u16* __restrict__ valS) {
    __shared__ int rcnt[256];
    __shared__ int cur[256];
    int b = blockIdx.x, tid = threadIdx.x;
    int j0 = bbase[b], j1 = bbase[b + 1];
    rcnt[tid] = 0;
    __syncthreads();
    for (int j = j0 + tid; j < j1; j += 256)
        atomicAdd(&rcnt[colT[j] >> 20], 1);
    __syncthreads();
    int own = rcnt[tid];
    for (int off = 1; off < 256; off <<= 1) {
        int t = (tid >= off) ? rcnt[tid - off] : 0;
        __syncthreads();
        rcnt[tid] += t;
        __syncthreads();
    }
    int start = j0 + rcnt[tid] - own;
    int row = b * 256 + tid;
    if (row < NNODES) rs[row] = start;
    if (b == 0 && tid == 0) rs[NNODES] = NEDGES;
    cur[tid] = start;
    __syncthreads();
    for (int j = j0 + tid; j < j1; j += 256) {
        u32 cx = colT[j];
        int p = atomicAdd(&cur[cx >> 20], 1);
        colS[p] = cx & 0xFFFFF;
        valS[p] = valT[j];
    }
}

// ---------------------------------------------------------------------------
// Pre-convert weights to fragment-ordered bf16 (R7, proven)
// ---------------------------------------------------------------------------
__global__ __launch_bounds__(256) void weights_prep(const float* __restrict__ Wg,
                                                    const float* __restrict__ Wb,
                                                    u16* __restrict__ wpre) {
    int layer = blockIdx.y;
    int idx = blockIdx.x * 256 + threadIdx.x;   // 0..8191
    int e = idx & 7, l = (idx >> 3) & 63, t = (idx >> 9) & 3, s = idx >> 11;
    int k = 32 * s + 8 * (l >> 4) + e;
    int n = 16 * t + (l & 15);
    float wv = (k < 64) ? Wg[layer * 4096 + k * 64 + n]
                        : Wb[layer * 4096 + (k - 64) * 64 + n];
    wpre[layer * 8192 + idx] = f2b(wv);
}

// ---------------------------------------------------------------------------
// SpMM (R7 body, proven 93us) + persistent grid: 2048 blocks, 8/CU, all
// resident waves sweep columns 0->100K together (rows are col-sorted).
// ---------------------------------------------------------------------------
__global__ __launch_bounds__(256, 8) void spmm(const int* __restrict__ rs,
                                               const int* __restrict__ colS,
                                               const u16* __restrict__ valS,
                                               const u32* __restrict__ ego32,
                                               u32*       __restrict__ side32) {
    int tid = threadIdx.x;
    int w = tid >> 6, lane = tid & 63;
    int h = lane >> 5, d = lane & 31;

    for (int row = blockIdx.x * 4 + w; row < NNODES; row += 8192) {
        int j0 = rs[row], j1 = rs[row + 1];

        float alo = 0.f, ahi = 0.f;
        float blo = 0.f, bhi = 0.f;
        int j = j0;
        for (; j + 16 <= j1; j += 16) {
            #pragma unroll
            for (int s = 0; s < 8; ++s) {
                int e = j + 2 * s + h;
                int c = colS[e];
                float v = us2f(valS[e]);
                u32 g = ego32[(size_t)c * 32 + d];
                if (s & 1) {
                    blo = fmaf(v, __uint_as_float(g << 16), blo);
                    bhi = fmaf(v, __uint_as_float(g & 0xFFFF0000u), bhi);
                } else {
                    alo = fmaf(v, __uint_as_float(g << 16), alo);
                    ahi = fmaf(v, __uint_as_float(g & 0xFFFF0000u), ahi);
                }
            }
        }
        for (; j < j1; j += 2) {
            int e = j + h;
            if (e < j1) {
                int c = colS[e];
                float v = us2f(valS[e]);
                u32 g = ego32[(size_t)c * 32 + d];
                alo = fmaf(v, __uint_as_float(g << 16), alo);
                ahi = fmaf(v, __uint_as_float(g & 0xFFFF0000u), ahi);
            }
        }
        float flo = alo + blo, fhi = ahi + bhi;
        flo += __shfl_xor(flo, 32, 64);
        fhi += __shfl_xor(fhi, 32, 64);
        if (h == 0)
            side32[(size_t)row * 32 + d] = (u32)f2b(flo) | ((u32)f2b(fhi) << 16);
    }
}

// ---------------------------------------------------------------------------
// Dense layer via MFMA (R7, proven): C = [side | ego*side] @ [Wg;Wb] + bias,
// leaky-relu; raw fp32 -> out col (layer+1); bf16 -> ego[N][64].
// ---------------------------------------------------------------------------
__global__ __launch_bounds__(256) void dense_mfma(const u16* __restrict__ side,
                                                  float*     __restrict__ out,
                                                  u16*       __restrict__ ego,
                                                  const u16* __restrict__ wpre,
                                                  const float* __restrict__ bg,
                                                  const float* __restrict__ bb,
                                                  int layer) {
    __shared__ u16 bfr[8192];
    __shared__ float lbias[64];

    int tid = threadIdx.x;
    {
        const uint4* src = (const uint4*)(wpre + layer * 8192);
        uint4* dst = (uint4*)bfr;
        #pragma unroll
        for (int i = 0; i < 4; ++i) dst[tid + 256 * i] = src[tid + 256 * i];
    }
    if (tid < 64) lbias[tid] = bg[layer * 64 + tid] + bb[layer * 64 + tid];
    __syncthreads();

    int w = tid >> 6, lane = tid & 63;
    int g = lane >> 4, m = lane & 15;
    int rb = blockIdx.x * 64 + w * 16;
    int rowc = min(rb + m, NNODES - 1);

    bf16x8 sf0 = *(const bf16x8*)(side + (size_t)rowc * DIM + g * 8);
    bf16x8 sf1 = *(const bf16x8*)(side + (size_t)rowc * DIM + 32 + g * 8);
    const float* erow = out + (size_t)rowc * OSTRIDE + layer * DIM;
    float4 e0a = *(const float4*)(erow + 8 * g);
    float4 e0b = *(const float4*)(erow + 8 * g + 4);
    float4 e1a = *(const float4*)(erow + 32 + 8 * g);
    float4 e1b = *(const float4*)(erow + 32 + 8 * g + 4);
    float ev0[8] = {e0a.x, e0a.y, e0a.z, e0a.w, e0b.x, e0b.y, e0b.z, e0b.w};
    float ev1[8] = {e1a.x, e1a.y, e1a.z, e1a.w, e1b.x, e1b.y, e1b.z, e1b.w};
    bf16x8 pf0, pf1;
    #pragma unroll
    for (int e = 0; e < 8; ++e) {
        pf0[e] = (short)f2b(us2f((u16)sf0[e]) * ev0[e]);
        pf1[e] = (short)f2b(us2f((u16)sf1[e]) * ev1[e]);
    }

    const bf16x8* B = (const bf16x8*)bfr;
    f32x4 acc[4];
    #pragma unroll
    for (int t = 0; t < 4; ++t) {
        acc[t] = (f32x4){0.f, 0.f, 0.f, 0.f};
        acc[t] = __builtin_amdgcn_mfma_f32_16x16x32_bf16(sf0, B[(0 * 4 + t) * 64 + lane], acc[t], 0, 0, 0);
        acc[t] = __builtin_amdgcn_mfma_f32_16x16x32_bf16(sf1, B[(1 * 4 + t) * 64 + lane], acc[t], 0, 0, 0);
        acc[t] = __builtin_amdgcn_mfma_f32_16x16x32_bf16(pf0, B[(2 * 4 + t) * 64 + lane], acc[t], 0, 0, 0);
        acc[t] = __builtin_amdgcn_mfma_f32_16x16x32_bf16(pf1, B[(3 * 4 + t) * 64 + lane], acc[t], 0, 0, 0);
    }

    #pragma unroll
    for (int t = 0; t < 4; ++t) {
        float bsv = lbias[16 * t + m];
        #pragma unroll
        for (int r = 0; r < 4; ++r) {
            int rw = rb + 4 * g + r;
            if (rw < NNODES) {
                float v = acc[t][r] + bsv;
                v = v >= 0.f ? v : 0.2f * v;
                out[(size_t)rw * OSTRIDE + (layer + 1) * DIM + 16 * t + m] = v;
                ego[(size_t)rw * DIM + 16 * t + m] = f2b(v);
            }
        }
    }
}

// ---------------------------------------------------------------------------
// L2-normalize the three layer column blocks (cols 64..255)
// ---------------------------------------------------------------------------
__global__ __launch_bounds__(256) void normalize_cols(float* __restrict__ out) {
    int node = blockIdx.x * 4 + (threadIdx.x >> 6);
    int lane = threadIdx.x & 63;
    float* p = out + (size_t)node * OSTRIDE + DIM;
    #pragma unroll
    for (int b = 0; b < 3; ++b) {
        float v = p[b * 64 + lane];
        float ss = v * v;
        #pragma unroll
        for (int m = 1; m < 64; m <<= 1) ss += __shfl_xor(ss, m, 64);
        p[b * 64 + lane] = v / fmaxf(sqrtf(ss), 1e-12f);
    }
}

// ---------------------------------------------------------------------------
extern "C" void kernel_launch(void* const* d_in, const int* in_sizes, int n_in,
                              void* d_out, int out_size, void* d_ws, size_t ws_size,
                              hipStream_t stream) {
    const float* ue   = (const float*)d_in[0];
    const float* ie   = (const float*)d_in[1];
    const float* Wg   = (const float*)d_in[2];
    const float* bg   = (const float*)d_in[3];
    const float* Wb   = (const float*)d_in[4];
    const float* bb   = (const float*)d_in[5];
    const int*   rows = (const int*)d_in[6];
    const int*   cols = (const int*)d_in[7];
    const float* vals = (const float*)d_in[8];
    float* out = (float*)d_out;

    // ws (45.3MB peak), time-multiplexed regions (E = NEDGES):
    //  [0,8E)      tmp int2        -- place output; later colS/valS + free
    //  [8E,12E)    colT u32        -- colsort output (dead after to_csr)
    //  [12E,14E)   valT u16
    //  [0,4E)      colS int        -- final CSR (overlaps dead tmp)
    //  [4E,5E)     valS u16
    //  [6E,10E)    egoA u16[N*64]  -- created after to_csr (overlaps dead tmp/colT)
    //  [10E,14E)   egoB + side     -- egoB u16[N*64]; side aliases egoB? no:
    //  side u16[N*64] lives at [10E,14E) only if egoB elsewhere -> use ping-pong:
    //  spmm writes side==egoOut region each layer (side IS the next ego staging?
    //  No: side and egoIn both needed; use egoA/egoB ping-pong + side at [10E... )
    char* base = (char*)d_ws;
    const size_t E = NEDGES;
    int2* tmp  = (int2*)base;
    u32*  colT = (u32*)(base + 8 * E);
    u16*  valT = (u16*)(base + 12 * E);
    int*  colS = (int*)base;
    u16*  valS = (u16*)(base + 4 * E);
    u16*  egoA = (u16*)(base + 6 * E);            // 12.8 MB  [6E,10E)
    u16*  egoB = (u16*)(base + 10 * E);           // 12.8 MB  [10E,14E)
    u16*  side = (u16*)(base + 14 * E);           // 12.8 MB  [14E,18E)
    int*  rs     = (int*)(base + 18 * E);
    int*  bcount  = rs + NNODES + 1;
    int*  bbase   = bcount + NBUCK;
    int*  bcursor = bbase + NBUCK + 1;
    u16*  wpre    = (u16*)(bcursor + NBUCK);

    hipMemsetAsync(bcount, 0, NBUCK * sizeof(int), stream);
    bucket_count<<<NPBLK, 256, 0, stream>>>(rows, bcount);
    bucket_scan<<<1, 512, 0, stream>>>(bcount, bbase, bcursor);
    bucket_place<<<NPBLK, 256, 0, stream>>>(rows, cols, vals, bcursor, tmp);
    bucket_colsort<<<NBUCK, 256, 0, stream>>>(bbase, tmp, colT, valT);
    bucket_to_csr<<<NBUCK, 256, 0, stream>>>(bbase, colT, valT, rs, colS, valS);

    weights_prep<<<dim3(32, 3), 256, 0, stream>>>(Wg, Wb, wpre);

    // init_ego AFTER to_csr: egoA overlaps dead tmp/colT regions
    init_ego<<<(NNODES * 16 + 255) / 256, 256, 0, stream>>>(ue, ie, out, (u32*)egoA);

    u16* ei = egoA; u16* eo = egoB;
    for (int l = 0; l < 3; ++l) {
        spmm<<<2048, 256, 0, stream>>>(rs, colS, valS, (const u32*)ei, (u32*)side);
        dense_mfma<<<(NNODES + 63) / 64, 256, 0, stream>>>(side, out, eo,
                                                           wpre, bg, bb, l);
        u16* t = ei; ei = eo; eo = t;
    }

    normalize_cols<<<NNODES / 4, 256, 0, stream>>>(out);
}